// Round 1
// baseline (338.252 us; speedup 1.0000x reference)
//
#include <hip/hip_runtime.h>

#define GDIM 128
#define NS   128
#define VD   28

__global__ __launch_bounds__(128) void plenoxel_kernel(
    const float* __restrict__ grid,
    const float* __restrict__ pos,
    const float* __restrict__ dist,
    const float* __restrict__ ang,
    float* __restrict__ out)
{
    const int r = blockIdx.x;
    const int s = threadIdx.x;   // sample index 0..127
    const int lane = s & 63;

    // ---- SH basis (per-ray, computed redundantly by every thread) ----
    const float th = ang[2 * r + 0];
    const float ph = ang[2 * r + 1];
    float st, ct, sp, cp;
    sincosf(th, &st, &ct);
    sincosf(ph, &sp, &cp);
    const float Y00 = 0.28209479177387814f;
    const float H3  = 0.4886025119029199f;
    const float H15 = 1.0925484305920792f;
    const float Q5  = 0.31539156525252005f;
    const float Q15 = 0.5462742152960396f;
    float Y[9];
    Y[0] = Y00;
    Y[1] = H3 * st * sp;
    Y[2] = H3 * ct;
    Y[3] = H3 * st * cp;
    Y[4] = H15 * (st * cp) * (st * sp);
    Y[5] = H15 * (st * sp) * ct;
    Y[6] = Q5 * (3.f * ct * ct - 1.f);
    Y[7] = H15 * (st * cp) * ct;
    Y[8] = Q15 * ((st * cp) * (st * cp) - (st * sp) * (st * sp));

    // ---- trilinear gather, SH dot folded in ----
    const float* p = pos + ((size_t)r * NS + s) * 3;
    const float x = p[0], y = p[1], z = p[2];
    const float fx0 = floorf(x), fy0 = floorf(y), fz0 = floorf(z);
    const int ix0 = (int)fx0, iy0 = (int)fy0, iz0 = (int)fz0;
    const float fx = x - fx0, fy = y - fy0, fz = z - fz0;

    int ix[2], iy[2], iz[2];
    ix[0] = min(max(ix0,     0), GDIM - 1);
    ix[1] = min(max(ix0 + 1, 0), GDIM - 1);
    iy[0] = min(max(iy0,     0), GDIM - 1);
    iy[1] = min(max(iy0 + 1, 0), GDIM - 1);
    iz[0] = min(max(iz0,     0), GDIM - 1);
    iz[1] = min(max(iz0 + 1, 0), GDIM - 1);
    const float wx[2] = {1.f - fx, fx};
    const float wy[2] = {1.f - fy, fy};
    const float wz[2] = {1.f - fz, fz};

    float sigma = 0.f, r0 = 0.f, r1 = 0.f, r2 = 0.f;
#pragma unroll
    for (int dx = 0; dx < 2; ++dx) {
#pragma unroll
        for (int dy = 0; dy < 2; ++dy) {
#pragma unroll
            for (int dz = 0; dz < 2; ++dz) {
                const float w = wx[dx] * wy[dy] * wz[dz];
                const size_t base =
                    (((size_t)ix[dx] * GDIM + iy[dy]) * GDIM + iz[dz]) * VD;
                const float4* g4 = (const float4*)(grid + base); // 112B, 16B aligned
                float f[28];
#pragma unroll
                for (int j = 0; j < 7; ++j) ((float4*)f)[j] = g4[j];
                sigma += w * f[0];
                float a0 = 0.f, a1 = 0.f, a2 = 0.f;
#pragma unroll
                for (int n = 0; n < 9; ++n) {
                    a0 += f[1 + n]  * Y[n];
                    a1 += f[10 + n] * Y[n];
                    a2 += f[19 + n] * Y[n];
                }
                r0 += w * a0;
                r1 += w * a1;
                r2 += w * a2;
            }
        }
    }

    // ---- att + inclusive cumsum along samples (matches jnp.cumsum) ----
    const float d = dist[(size_t)r * NS + s];
    const float att = expf(-sigma * d);

    float t = att;
#pragma unroll
    for (int o = 1; o < 64; o <<= 1) {
        const float v = __shfl_up(t, (unsigned)o, 64);
        if (lane >= o) t += v;
    }
    __shared__ float wave0_total;
    if (s == 63) wave0_total = t;
    __syncthreads();
    const float trans = t + (s >= 64 ? wave0_total : 0.f);
    const float weight = trans * (1.f - att);

    // ---- weighted RGB, block reduction over samples ----
    float w0 = weight * r0, w1 = weight * r1, w2 = weight * r2;
#pragma unroll
    for (int o = 32; o > 0; o >>= 1) {
        w0 += __shfl_down(w0, (unsigned)o, 64);
        w1 += __shfl_down(w1, (unsigned)o, 64);
        w2 += __shfl_down(w2, (unsigned)o, 64);
    }
    __shared__ float part[2][3];
    if (lane == 0) {
        const int wv = s >> 6;
        part[wv][0] = w0; part[wv][1] = w1; part[wv][2] = w2;
    }
    __syncthreads();
    if (s == 0) {
        out[(size_t)r * 3 + 0] = part[0][0] + part[1][0];
        out[(size_t)r * 3 + 1] = part[0][1] + part[1][1];
        out[(size_t)r * 3 + 2] = part[0][2] + part[1][2];
    }
}

extern "C" void kernel_launch(void* const* d_in, const int* in_sizes, int n_in,
                              void* d_out, int out_size, void* d_ws, size_t ws_size,
                              hipStream_t stream) {
    const float* grid = (const float*)d_in[0];
    const float* pos  = (const float*)d_in[1];
    const float* dst  = (const float*)d_in[2];
    const float* ang  = (const float*)d_in[3];
    float* out = (float*)d_out;

    const int R = in_sizes[3] / 2;   // 2048 rays
    plenoxel_kernel<<<R, NS, 0, stream>>>(grid, pos, dst, ang, out);
}